// Round 1
// baseline (278.466 us; speedup 1.0000x reference)
//
#include <hip/hip_runtime.h>
#include <stdint.h>

#define NODE 256
#define DIM 256

using f32x4  = __attribute__((ext_vector_type(4))) float;
using short8 = __attribute__((ext_vector_type(8))) short;

static __device__ __forceinline__ unsigned short f2bf(float f) {
  unsigned u = __float_as_uint(f);
  unsigned r = (u + 0x7FFFu + ((u >> 16) & 1u)) >> 16;
  return (unsigned short)r;
}

static __device__ __forceinline__ float tanh_fast(float v) {
  // tanh(v) = 1 - 2/(1+exp(2v)); saturates correctly at +/-inf
  float e = __expf(2.0f * v);
  return 1.0f - 2.0f / (1.0f + e);
}

// ---------------------------------------------------------------- prep ------
// blocks 0..511: convert x (f32) -> xbf (bf16).  blocks 512..767: WpT = Wp^T.
__global__ __launch_bounds__(256) void k_prep(const float* __restrict__ x,
                                              const float* __restrict__ Wp,
                                              unsigned short* __restrict__ xbf,
                                              float* __restrict__ WpT) {
  __shared__ float tile[16][17];
  const int bid = blockIdx.x, tid = threadIdx.x;
  if (bid < 512) {
    int idx = bid * 256 + tid;                       // float4 index, 131072 total
    float4 v = ((const float4*)x)[idx];
    unsigned long long pk =
        (unsigned long long)f2bf(v.x)
      | ((unsigned long long)f2bf(v.y) << 16)
      | ((unsigned long long)f2bf(v.z) << 32)
      | ((unsigned long long)f2bf(v.w) << 48);
    ((unsigned long long*)xbf)[idx] = pk;
  } else {
    int t  = bid - 512;                              // 256 tiles of 16x16
    int by = t >> 4, bx = t & 15;
    int tx = tid & 15, ty = tid >> 4;
    tile[ty][tx] = Wp[(by*16 + ty)*256 + (bx*16 + tx)];
    __syncthreads();
    WpT[(bx*16 + ty)*256 + (by*16 + tx)] = tile[tx][ty];
  }
}

// --------------------------------------------------------------- scores -----
// One workgroup per (b,n).  8 waves (512 thr).  D[e][m] = sum_d Zt[e,d]*x[b,m,d]
// with Zt[e,d] = x[b,n,d]*WpT[e,d].  Zt staged in LDS bf16, fragment-linear.
// Waves: 2 e-waves (128 e each) x 4 m-waves (64 m each).
__global__ __launch_bounds__(512, 2) void k_scores(
    const float* __restrict__ x, const unsigned short* __restrict__ xbf,
    const float* __restrict__ WpT, const float* __restrict__ bp,
    const float* __restrict__ watt, float* __restrict__ scores) {
  __shared__ unsigned char zl[131072];
  __shared__ float ps[2][256];
  __shared__ float bpl[256], wal[256];

  const int tid = threadIdx.x;
  const int l = tid & 63, w = tid >> 6;
  const int bb = blockIdx.x >> 8, n = blockIdx.x & 255;

  if (tid < 256) { bpl[tid] = bp[tid]; wal[tid] = watt[tid]; }

  // ---- stage Zt into LDS in fragment-linear layout -------------------------
  // faddr(e,d) = ((e>>4)*8 + (d>>5))*1024 + (((d>>3)&3)*16 + (e&15))*16 + (d&7)*2
  {
    const float* xrow = x + (size_t)(bb*NODE + n) * DIM;
    const int lg = l >> 4, lr = l & 15;
    #pragma unroll
    for (int eb2 = 0; eb2 < 2; ++eb2) {
      int e = (w*2 + eb2)*16 + lr;
      const float* wrow = WpT + (size_t)e * 256;
      #pragma unroll
      for (int db = 0; db < 16; ++db) {
        int d = lg*4 + db*16;
        float4 wp = *(const float4*)(wrow + d);
        float4 xn = *(const float4*)(xrow + d);
        unsigned long long pk =
            (unsigned long long)f2bf(wp.x * xn.x)
          | ((unsigned long long)f2bf(wp.y * xn.y) << 16)
          | ((unsigned long long)f2bf(wp.z * xn.z) << 32)
          | ((unsigned long long)f2bf(wp.w * xn.w) << 48);
        int addr = ((e>>4)*8 + (d>>5))*1024 + (((d>>3)&3)*16 + (e&15))*16 + (d&7)*2;
        *(unsigned long long*)(zl + addr) = pk;
      }
    }
  }
  __syncthreads();

  const int we = w >> 2;        // 0..1  e-wave  (128 e)
  const int wm = w & 3;         // 0..3  m-wave  (64 m)

  f32x4 acc[8][4];
  #pragma unroll
  for (int eb = 0; eb < 8; ++eb)
    #pragma unroll
    for (int j = 0; j < 4; ++j)
      acc[eb][j] = (f32x4){0.f, 0.f, 0.f, 0.f};

  const unsigned short* xb = xbf + (size_t)bb * (NODE * DIM);
  const int lr = l & 15, lg = l >> 4;

  short8 bcur[4], bnxt[4];
  #pragma unroll
  for (int j = 0; j < 4; ++j) {
    int m = wm*64 + j*16 + lr;
    bcur[j] = *(const short8*)(xb + (size_t)m*256 + 0*32 + lg*8);
  }

  for (int k = 0; k < 8; ++k) {
    if (k < 7) {
      #pragma unroll
      for (int j = 0; j < 4; ++j) {
        int m = wm*64 + j*16 + lr;
        bnxt[j] = *(const short8*)(xb + (size_t)m*256 + (k+1)*32 + lg*8);
      }
    }
    #pragma unroll
    for (int eb = 0; eb < 8; ++eb) {
      short8 af = *(const short8*)(zl + (((we*8 + eb)*8 + k) << 10) + (l << 4));
      #pragma unroll
      for (int j = 0; j < 4; ++j)
        acc[eb][j] = __builtin_amdgcn_mfma_f32_16x16x32_bf16(af, bcur[j], acc[eb][j], 0, 0, 0);
    }
    if (k < 7) {
      #pragma unroll
      for (int j = 0; j < 4; ++j) bcur[j] = bnxt[j];
    }
  }

  // ---- epilogue: tanh + weighted e-reduction -------------------------------
  float p[4] = {0.f, 0.f, 0.f, 0.f};
  #pragma unroll
  for (int eb = 0; eb < 8; ++eb) {
    #pragma unroll
    for (int r = 0; r < 4; ++r) {
      int e = we*128 + eb*16 + lg*4 + r;
      float bpe = bpl[e], wae = wal[e];
      #pragma unroll
      for (int j = 0; j < 4; ++j) {
        float v = acc[eb][j][r] + bpe;
        p[j] += tanh_fast(v) * wae;
      }
    }
  }
  #pragma unroll
  for (int j = 0; j < 4; ++j) {
    p[j] += __shfl_xor(p[j], 16);
    p[j] += __shfl_xor(p[j], 32);
  }
  if (lg == 0) {
    #pragma unroll
    for (int j = 0; j < 4; ++j) ps[we][wm*64 + j*16 + lr] = p[j];
  }
  __syncthreads();
  if (tid < 256)
    scores[(size_t)blockIdx.x * 256 + tid] = ps[0][tid] + ps[1][tid];
}

// -------------------------------------------------------------- softmax -----
// softmax over n (axis=1) for each (b,m).  Grid: 8 b x 4 m-tiles of 64.
__global__ __launch_bounds__(256) void k_softmax(float* __restrict__ sc) {
  __shared__ float tile[256][65];
  __shared__ float red[4][64];
  const int t = threadIdx.x;
  const int bb = blockIdx.x >> 2, mt = blockIdx.x & 3;
  const int m0 = mt * 64;

  for (int c = 0; c < 64; ++c) {
    int nn = c*4 + (t >> 6);
    tile[nn][t & 63] = sc[(size_t)(bb*256 + nn)*256 + m0 + (t & 63)];
  }
  __syncthreads();
  const int col = t & 63, g = t >> 6;
  float mx = -1e30f;
  for (int k2 = 0; k2 < 64; ++k2) mx = fmaxf(mx, tile[g*64 + k2][col]);
  red[g][col] = mx;
  __syncthreads();
  float M = fmaxf(fmaxf(red[0][col], red[1][col]), fmaxf(red[2][col], red[3][col]));
  float sm = 0.f;
  for (int k2 = 0; k2 < 64; ++k2) {
    float ev = __expf(tile[g*64 + k2][col] - M);
    tile[g*64 + k2][col] = ev;
    sm += ev;
  }
  __syncthreads();
  red[g][col] = sm;
  __syncthreads();
  float inv = 1.0f / (red[0][col] + red[1][col] + red[2][col] + red[3][col]);
  for (int k2 = 0; k2 < 64; ++k2) tile[g*64 + k2][col] *= inv;
  __syncthreads();
  for (int c = 0; c < 64; ++c) {
    int nn = c*4 + (t >> 6);
    sc[(size_t)(bb*256 + nn)*256 + m0 + (t & 63)] = tile[nn][t & 63];
  }
}

// -------------------------------------------------------------- aggproj -----
// out[n,e] = (att[n,:] @ x_b) @ W1 + x_n @ W2 + b1 + b2, 8 n-rows per block.
// Also emits per-block BN partial sums.
__global__ __launch_bounds__(256) void k_aggproj(
    const float* __restrict__ x, const float* __restrict__ att,
    const float* __restrict__ W1, const float* __restrict__ b1,
    const float* __restrict__ W2, const float* __restrict__ b2,
    float* __restrict__ out, float* __restrict__ bnpart) {
  __shared__ float att8[8][256];
  __shared__ float xn8[8][256];
  __shared__ float agg8[8][256];
  const int t = threadIdx.x;
  const int bb = blockIdx.x >> 5, ng = blockIdx.x & 31;
  const int n0 = ng * 8;

  #pragma unroll
  for (int i = 0; i < 8; ++i) {
    att8[i][t] = att[(size_t)(bb*256 + n0 + i)*256 + t];
    xn8[i][t]  = x  [(size_t)(bb*256 + n0 + i)*256 + t];
  }
  __syncthreads();

  float ar[8] = {0.f,0.f,0.f,0.f,0.f,0.f,0.f,0.f};
  for (int m4 = 0; m4 < 64; ++m4) {
    int m = m4 * 4;
    float xv0 = x[(size_t)(bb*256 + m + 0)*256 + t];
    float xv1 = x[(size_t)(bb*256 + m + 1)*256 + t];
    float xv2 = x[(size_t)(bb*256 + m + 2)*256 + t];
    float xv3 = x[(size_t)(bb*256 + m + 3)*256 + t];
    #pragma unroll
    for (int i = 0; i < 8; ++i) {
      float4 av = *(const float4*)&att8[i][m];
      ar[i] += av.x*xv0 + av.y*xv1 + av.z*xv2 + av.w*xv3;
    }
  }
  #pragma unroll
  for (int i = 0; i < 8; ++i) agg8[i][t] = ar[i];
  __syncthreads();

  float o[8];
  float bsum = b1[t] + b2[t];
  #pragma unroll
  for (int i = 0; i < 8; ++i) o[i] = bsum;
  for (int d4 = 0; d4 < 64; ++d4) {
    int d = d4 * 4;
    float w10 = W1[(d+0)*256 + t], w11 = W1[(d+1)*256 + t];
    float w12 = W1[(d+2)*256 + t], w13 = W1[(d+3)*256 + t];
    float w20 = W2[(d+0)*256 + t], w21 = W2[(d+1)*256 + t];
    float w22 = W2[(d+2)*256 + t], w23 = W2[(d+3)*256 + t];
    #pragma unroll
    for (int i = 0; i < 8; ++i) {
      float4 ag = *(const float4*)&agg8[i][d];
      float4 xn = *(const float4*)&xn8[i][d];
      o[i] += ag.x*w10 + ag.y*w11 + ag.z*w12 + ag.w*w13
            + xn.x*w20 + xn.y*w21 + xn.z*w22 + xn.w*w23;
    }
  }
  float s1 = 0.f, s2 = 0.f;
  #pragma unroll
  for (int i = 0; i < 8; ++i) {
    out[(size_t)(bb*256 + n0 + i)*256 + t] = o[i];
    s1 += o[i];
    s2 += o[i]*o[i];
  }
  bnpart[(size_t)blockIdx.x*512 + t]       = s1;
  bnpart[(size_t)blockIdx.x*512 + 256 + t] = s2;
}

// -------------------------------------------------------------- bnstats -----
__global__ __launch_bounds__(256) void k_bnstats(const float* __restrict__ bnpart,
                                                 float* __restrict__ bnacc) {
  __shared__ float r4[4];
  const int s = blockIdx.x;         // 0..511
  const int t = threadIdx.x;        // one partial per block index
  float v = bnpart[(size_t)t*512 + s];
  v += __shfl_xor(v, 1);
  v += __shfl_xor(v, 2);
  v += __shfl_xor(v, 4);
  v += __shfl_xor(v, 8);
  v += __shfl_xor(v, 16);
  v += __shfl_xor(v, 32);
  if ((t & 63) == 0) r4[t >> 6] = v;
  __syncthreads();
  if (t == 0) bnacc[s] = r4[0] + r4[1] + r4[2] + r4[3];
}

// -------------------------------------------------------------- bnapply -----
__global__ __launch_bounds__(256) void k_bnapply(float* __restrict__ io,
                                                 const float* __restrict__ bnacc,
                                                 const float* __restrict__ gamma,
                                                 const float* __restrict__ beta) {
  const int e = threadIdx.x;
  float mean = bnacc[e] * (1.0f/2048.0f);
  float var  = bnacc[256 + e] * (1.0f/2048.0f) - mean*mean;
  float scl  = rsqrtf(var + 1e-5f) * gamma[e];
  float sh   = beta[e] - mean*scl;
  for (int r = blockIdx.x; r < 2048; r += gridDim.x) {
    float v = io[(size_t)r*256 + e];
    float y = v*scl + sh;
    float s = (y > 0.f) ? 1.0507009873554805f * y
                        : 1.7580993408473766f * (__expf(y) - 1.0f);
    io[(size_t)r*256 + e] = s;
  }
}

// ---------------------------------------------------------------------------
extern "C" void kernel_launch(void* const* d_in, const int* in_sizes, int n_in,
                              void* d_out, int out_size, void* d_ws, size_t ws_size,
                              hipStream_t stream) {
  const float* x     = (const float*)d_in[0];
  const float* Wp    = (const float*)d_in[1];
  const float* bp    = (const float*)d_in[2];
  const float* watt  = (const float*)d_in[3];
  const float* W1    = (const float*)d_in[4];
  const float* b1    = (const float*)d_in[5];
  const float* W2    = (const float*)d_in[6];
  const float* b2    = (const float*)d_in[7];
  const float* gamma = (const float*)d_in[8];
  const float* beta  = (const float*)d_in[9];
  float* out = (float*)d_out;
  float* ws  = (float*)d_ws;

  float* scores = ws;                                // 524288 f32 (scores -> att)
  float* WpT    = ws + 524288;                       // 65536 f32
  float* bnpart = ws + 524288 + 65536;               // 256*512 f32
  float* bnacc  = bnpart + 131072;                   // 512 f32
  unsigned short* xbf = (unsigned short*)(bnacc + 512);  // 524288 bf16

  k_prep   <<<768,  256, 0, stream>>>(x, Wp, xbf, WpT);
  k_scores <<<2048, 512, 0, stream>>>(x, xbf, WpT, bp, watt, scores);
  k_softmax<<<32,   256, 0, stream>>>(scores);
  k_aggproj<<<256,  256, 0, stream>>>(x, scores, W1, b1, W2, b2, out, bnpart);
  k_bnstats<<<512,  256, 0, stream>>>(bnpart, bnacc);
  k_bnapply<<<256,  256, 0, stream>>>(out, bnacc, gamma, beta);
}

// Round 2
// 159.365 us; speedup vs baseline: 1.7473x; 1.7473x over previous
//
#include <hip/hip_runtime.h>
#include <stdint.h>

using f32x4  = __attribute__((ext_vector_type(4))) float;
using short8 = __attribute__((ext_vector_type(8))) short;

#define C2LOG2E 2.8853900817779268f   // 2*log2(e)

static __device__ __forceinline__ unsigned cvt_pk_bf16(float lo, float hi) {
  unsigned r;
  asm("v_cvt_pk_bf16_f32 %0, %1, %2" : "=v"(r) : "v"(lo), "v"(hi));
  return r;
}

// ---------------------------------------------------------------- prep ------
// Pre-pack x and Wp into MFMA fragment-linear bf16 layouts.
// Frag layout of a [16 rows x 32 k] bf16 tile (1024 B block):
//   byte(row,kk) = ((kk>>3)*16 + row)*16 + (kk&7)*2     (kk = k-elem 0..31)
// so lane l (=lg*16+lr) reads its 16B A/B fragment at block_base + l*16.
// xfrag:  per b: blocks (mt,k) of x[b][mt*16+row][k*32+kk]      (8*128 KB)
// wpfrag: per h: blocks (et,k) of Wp[k*32+kk][h*128+et*16+row]  (2*64 KB)
__global__ __launch_bounds__(256) void k_prep(const float* __restrict__ x,
                                              const float* __restrict__ Wp,
                                              unsigned int* __restrict__ xfrag,
                                              unsigned int* __restrict__ wpfrag) {
  const int bid = blockIdx.x, t = threadIdx.x;
  const int lg = (t >> 6) & 3, row = (t >> 2) & 15, tp = t & 3;
  if (bid < 1024) {
    const int b = bid >> 7, mt = (bid >> 3) & 15, k = bid & 7;
    const int m = mt * 16 + row;
    const int d = k * 32 + lg * 8 + tp * 2;
    float2 v = *(const float2*)(x + ((size_t)(b * 256 + m)) * 256 + d);
    xfrag[(size_t)b * 32768 + (mt * 8 + k) * 256 + t] = cvt_pk_bf16(v.x, v.y);
  } else {
    const int b2 = bid - 1024;                 // 0..127
    const int h = b2 >> 6, et = (b2 >> 3) & 7, k = b2 & 7;
    const int e = h * 128 + et * 16 + row;
    const int d = k * 32 + lg * 8 + tp * 2;
    float v0 = Wp[(size_t)d * 256 + e];
    float v1 = Wp[(size_t)(d + 1) * 256 + e];
    wpfrag[(size_t)h * 16384 + (et * 8 + k) * 256 + t] = cvt_pk_bf16(v0, v1);
  }
}

// --------------------------------------------------------------- scores -----
// Block = (b, n, e-half).  512 thr / 8 waves; wave w owns m-tiles {2w,2w+1},
// all 8 e-tiles of the half.  A = (x_n ∘ x_m) built in regs; B = Wp from LDS.
// D[row=m, col=e].  Epilogue: tanh -> * w_att -> reduce over e (in-reg + shfl).
__global__ __launch_bounds__(512, 4) void k_scores(
    const float* __restrict__ x, const unsigned int* __restrict__ xfrag,
    const unsigned int* __restrict__ wpfrag, const float* __restrict__ bp,
    const float* __restrict__ watt, float* __restrict__ sp) {
  __shared__ unsigned char wplds[65536];
  __shared__ float bpl[128], wal[128];

  const int tid = threadIdx.x;
  const int l = tid & 63, w = tid >> 6;
  const int lr = l & 15, lg = l >> 4;
  const int bid = blockIdx.x;
  const int h = bid & 1, n = (bid >> 1) & 255, bb = bid >> 9;

  // stage Wp-frag half (64 KB) straight to LDS, linear, zero VALU
  {
    const unsigned char* src = (const unsigned char*)(wpfrag + (size_t)h * 16384);
    #pragma unroll
    for (int it = 0; it < 8; ++it) {
      __builtin_amdgcn_global_load_lds(
          (const __attribute__((address_space(1))) unsigned int*)(src + it * 8192 + w * 1024 + l * 16),
          (__attribute__((address_space(3))) unsigned int*)(&wplds[it * 8192 + w * 1024]),
          16, 0, 0);
    }
  }
  if (tid < 128) {
    bpl[tid] = bp[h * 128 + tid] * C2LOG2E;
    wal[tid] = watt[h * 128 + tid];
  }
  __syncthreads();

  f32x4 acc[2][8];
  #pragma unroll
  for (int j = 0; j < 2; ++j)
    #pragma unroll
    for (int et = 0; et < 8; ++et)
      acc[j][et] = (f32x4){0.f, 0.f, 0.f, 0.f};

  const float* xrow = x + (size_t)(bb * 256 + n) * 256;
  const unsigned char* xfb = (const unsigned char*)xfrag + (size_t)bb * 131072;

  for (int k = 0; k < 8; ++k) {
    float4 xnl = *(const float4*)(xrow + k * 32 + lg * 8);
    float4 xnh = *(const float4*)(xrow + k * 32 + lg * 8 + 4);
    uint4 xm0 = *(const uint4*)(xfb + (((w * 2 + 0) * 8 + k) << 10) + l * 16);
    uint4 xm1 = *(const uint4*)(xfb + (((w * 2 + 1) * 8 + k) << 10) + l * 16);

    unsigned a0u[4], a1u[4];
    {
      float xn0 = xnl.x, xn1 = xnl.y, xn2 = xnl.z, xn3 = xnl.w;
      float xn4 = xnh.x, xn5 = xnh.y, xn6 = xnh.z, xn7 = xnh.w;
      a0u[0] = cvt_pk_bf16(__uint_as_float(xm0.x << 16) * xn0,
                           __uint_as_float(xm0.x & 0xffff0000u) * xn1);
      a0u[1] = cvt_pk_bf16(__uint_as_float(xm0.y << 16) * xn2,
                           __uint_as_float(xm0.y & 0xffff0000u) * xn3);
      a0u[2] = cvt_pk_bf16(__uint_as_float(xm0.z << 16) * xn4,
                           __uint_as_float(xm0.z & 0xffff0000u) * xn5);
      a0u[3] = cvt_pk_bf16(__uint_as_float(xm0.w << 16) * xn6,
                           __uint_as_float(xm0.w & 0xffff0000u) * xn7);
      a1u[0] = cvt_pk_bf16(__uint_as_float(xm1.x << 16) * xn0,
                           __uint_as_float(xm1.x & 0xffff0000u) * xn1);
      a1u[1] = cvt_pk_bf16(__uint_as_float(xm1.y << 16) * xn2,
                           __uint_as_float(xm1.y & 0xffff0000u) * xn3);
      a1u[2] = cvt_pk_bf16(__uint_as_float(xm1.z << 16) * xn4,
                           __uint_as_float(xm1.z & 0xffff0000u) * xn5);
      a1u[3] = cvt_pk_bf16(__uint_as_float(xm1.w << 16) * xn6,
                           __uint_as_float(xm1.w & 0xffff0000u) * xn7);
    }
    union { unsigned u[4]; short8 s; } ua0, ua1;
    ua0.u[0] = a0u[0]; ua0.u[1] = a0u[1]; ua0.u[2] = a0u[2]; ua0.u[3] = a0u[3];
    ua1.u[0] = a1u[0]; ua1.u[1] = a1u[1]; ua1.u[2] = a1u[2]; ua1.u[3] = a1u[3];
    short8 a0 = ua0.s, a1 = ua1.s;

    #pragma unroll
    for (int et = 0; et < 8; ++et) {
      short8 bf = *(const short8*)(&wplds[((et * 8 + k) << 10) + l * 16]);
      acc[0][et] = __builtin_amdgcn_mfma_f32_16x16x32_bf16(a0, bf, acc[0][et], 0, 0, 0);
      acc[1][et] = __builtin_amdgcn_mfma_f32_16x16x32_bf16(a1, bf, acc[1][et], 0, 0, 0);
    }
  }

  // ---- epilogue: tanh (exp2-domain) * w_att, reduce over e -----------------
  float pj[8] = {0.f, 0.f, 0.f, 0.f, 0.f, 0.f, 0.f, 0.f};
  #pragma unroll
  for (int et = 0; et < 8; ++et) {
    float bpe = bpl[et * 16 + lr];
    float we  = wal[et * 16 + lr];
    #pragma unroll
    for (int j = 0; j < 2; ++j)
      #pragma unroll
      for (int r = 0; r < 4; ++r) {
        float v = fmaf(acc[j][et][r], C2LOG2E, bpe);
        float ex = exp2f(v);
        float th = fmaf(-2.0f, __builtin_amdgcn_rcpf(1.0f + ex), 1.0f);
        pj[j * 4 + r] = fmaf(th, we, pj[j * 4 + r]);
      }
  }
  #pragma unroll
  for (int i = 0; i < 8; ++i) {
    pj[i] += __shfl_xor(pj[i], 1);
    pj[i] += __shfl_xor(pj[i], 2);
    pj[i] += __shfl_xor(pj[i], 4);
    pj[i] += __shfl_xor(pj[i], 8);
  }
  if (lr == 0) {
    float* dst = sp + (size_t)h * 524288 + (size_t)(bb * 256 + n) * 256;
    #pragma unroll
    for (int j = 0; j < 2; ++j)
      #pragma unroll
      for (int r = 0; r < 4; ++r)
        dst[(w * 2 + j) * 16 + lg * 4 + r] = pj[j * 4 + r];
  }
}

// -------------------------------------------------------------- softmax -----
// sum the two e-half partials, softmax over n (axis=1), write att into sp[0].
__global__ __launch_bounds__(256) void k_softmax(float* __restrict__ sp) {
  __shared__ float tile[256][65];
  __shared__ float red[4][64];
  const int t = threadIdx.x;
  const int bb = blockIdx.x >> 2, mt = blockIdx.x & 3;
  const int m0 = mt * 64;

  for (int c = 0; c < 64; ++c) {
    int nn = c * 4 + (t >> 6);
    size_t idx = (size_t)(bb * 256 + nn) * 256 + m0 + (t & 63);
    tile[nn][t & 63] = sp[idx] + sp[524288 + idx];
  }
  __syncthreads();
  const int col = t & 63, g = t >> 6;
  float mx = -1e30f;
  for (int k2 = 0; k2 < 64; ++k2) mx = fmaxf(mx, tile[g * 64 + k2][col]);
  red[g][col] = mx;
  __syncthreads();
  float M = fmaxf(fmaxf(red[0][col], red[1][col]), fmaxf(red[2][col], red[3][col]));
  float sm = 0.f;
  for (int k2 = 0; k2 < 64; ++k2) {
    float ev = __expf(tile[g * 64 + k2][col] - M);
    tile[g * 64 + k2][col] = ev;
    sm += ev;
  }
  __syncthreads();
  red[g][col] = sm;
  __syncthreads();
  float inv = 1.0f / (red[0][col] + red[1][col] + red[2][col] + red[3][col]);
  for (int k2 = 0; k2 < 64; ++k2) tile[g * 64 + k2][col] *= inv;
  __syncthreads();
  for (int c = 0; c < 64; ++c) {
    int nn = c * 4 + (t >> 6);
    sp[(size_t)(bb * 256 + nn) * 256 + m0 + (t & 63)] = tile[nn][t & 63];
  }
}

// -------------------------------------------------------------- aggproj -----
__global__ __launch_bounds__(256) void k_aggproj(
    const float* __restrict__ x, const float* __restrict__ att,
    const float* __restrict__ W1, const float* __restrict__ b1,
    const float* __restrict__ W2, const float* __restrict__ b2,
    float* __restrict__ out, float* __restrict__ bnpart) {
  __shared__ float att8[8][256];
  __shared__ float xn8[8][256];
  __shared__ float agg8[8][256];
  const int t = threadIdx.x;
  const int bb = blockIdx.x >> 5, ng = blockIdx.x & 31;
  const int n0 = ng * 8;

  #pragma unroll
  for (int i = 0; i < 8; ++i) {
    att8[i][t] = att[(size_t)(bb * 256 + n0 + i) * 256 + t];
    xn8[i][t]  = x  [(size_t)(bb * 256 + n0 + i) * 256 + t];
  }
  __syncthreads();

  float ar[8] = {0.f, 0.f, 0.f, 0.f, 0.f, 0.f, 0.f, 0.f};
  for (int m4 = 0; m4 < 64; ++m4) {
    int m = m4 * 4;
    float xv0 = x[(size_t)(bb * 256 + m + 0) * 256 + t];
    float xv1 = x[(size_t)(bb * 256 + m + 1) * 256 + t];
    float xv2 = x[(size_t)(bb * 256 + m + 2) * 256 + t];
    float xv3 = x[(size_t)(bb * 256 + m + 3) * 256 + t];
    #pragma unroll
    for (int i = 0; i < 8; ++i) {
      float4 av = *(const float4*)&att8[i][m];
      ar[i] += av.x * xv0 + av.y * xv1 + av.z * xv2 + av.w * xv3;
    }
  }
  #pragma unroll
  for (int i = 0; i < 8; ++i) agg8[i][t] = ar[i];
  __syncthreads();

  float o[8];
  float bsum = b1[t] + b2[t];
  #pragma unroll
  for (int i = 0; i < 8; ++i) o[i] = bsum;
  for (int d4 = 0; d4 < 64; ++d4) {
    int d = d4 * 4;
    float w10 = W1[(d + 0) * 256 + t], w11 = W1[(d + 1) * 256 + t];
    float w12 = W1[(d + 2) * 256 + t], w13 = W1[(d + 3) * 256 + t];
    float w20 = W2[(d + 0) * 256 + t], w21 = W2[(d + 1) * 256 + t];
    float w22 = W2[(d + 2) * 256 + t], w23 = W2[(d + 3) * 256 + t];
    #pragma unroll
    for (int i = 0; i < 8; ++i) {
      float4 ag = *(const float4*)&agg8[i][d];
      float4 xn = *(const float4*)&xn8[i][d];
      o[i] += ag.x * w10 + ag.y * w11 + ag.z * w12 + ag.w * w13
            + xn.x * w20 + xn.y * w21 + xn.z * w22 + xn.w * w23;
    }
  }
  float s1 = 0.f, s2 = 0.f;
  #pragma unroll
  for (int i = 0; i < 8; ++i) {
    out[(size_t)(bb * 256 + n0 + i) * 256 + t] = o[i];
    s1 += o[i];
    s2 += o[i] * o[i];
  }
  bnpart[(size_t)blockIdx.x * 512 + t]       = s1;
  bnpart[(size_t)blockIdx.x * 512 + 256 + t] = s2;
}

// -------------------------------------------------------------- bnstats -----
__global__ __launch_bounds__(256) void k_bnstats(const float* __restrict__ bnpart,
                                                 float* __restrict__ bnacc) {
  __shared__ float r4[4];
  const int s = blockIdx.x;   // 0..511
  const int t = threadIdx.x;
  float v = bnpart[(size_t)t * 512 + s];
  v += __shfl_xor(v, 1);
  v += __shfl_xor(v, 2);
  v += __shfl_xor(v, 4);
  v += __shfl_xor(v, 8);
  v += __shfl_xor(v, 16);
  v += __shfl_xor(v, 32);
  if ((t & 63) == 0) r4[t >> 6] = v;
  __syncthreads();
  if (t == 0) bnacc[s] = r4[0] + r4[1] + r4[2] + r4[3];
}

// -------------------------------------------------------------- bnapply -----
__global__ __launch_bounds__(256) void k_bnapply(float* __restrict__ io,
                                                 const float* __restrict__ bnacc,
                                                 const float* __restrict__ gamma,
                                                 const float* __restrict__ beta) {
  const int e = threadIdx.x;
  float mean = bnacc[e] * (1.0f / 2048.0f);
  float var  = bnacc[256 + e] * (1.0f / 2048.0f) - mean * mean;
  float scl  = rsqrtf(var + 1e-5f) * gamma[e];
  float sh   = beta[e] - mean * scl;
  for (int r = blockIdx.x; r < 2048; r += gridDim.x) {
    float v = io[(size_t)r * 256 + e];
    float y = v * scl + sh;
    float s = (y > 0.f) ? 1.0507009873554805f * y
                        : 1.7580993408473766f * (__expf(y) - 1.0f);
    io[(size_t)r * 256 + e] = s;
  }
}

// ---------------------------------------------------------------------------
extern "C" void kernel_launch(void* const* d_in, const int* in_sizes, int n_in,
                              void* d_out, int out_size, void* d_ws, size_t ws_size,
                              hipStream_t stream) {
  const float* x     = (const float*)d_in[0];
  const float* Wp    = (const float*)d_in[1];
  const float* bp    = (const float*)d_in[2];
  const float* watt  = (const float*)d_in[3];
  const float* W1    = (const float*)d_in[4];
  const float* b1    = (const float*)d_in[5];
  const float* W2    = (const float*)d_in[6];
  const float* b2    = (const float*)d_in[7];
  const float* gamma = (const float*)d_in[8];
  const float* beta  = (const float*)d_in[9];
  float* out = (float*)d_out;
  float* ws  = (float*)d_ws;

  float* sp = ws;                                        // [2][524288] f32
  unsigned int* wpfragG = (unsigned int*)(ws + 1048576); // 32768 dwords
  unsigned int* xfragG  = wpfragG + 32768;               // 262144 dwords
  float* bnpart = ws + 524288;                           // aliases sp[1] (dead after softmax)
  float* bnacc  = bnpart + 131072;

  k_prep   <<<1152, 256, 0, stream>>>(x, Wp, xfragG, wpfragG);
  k_scores <<<4096, 512, 0, stream>>>(x, xfragG, wpfragG, bp, watt, sp);
  k_softmax<<<32,   256, 0, stream>>>(sp);
  k_aggproj<<<256,  256, 0, stream>>>(x, sp, W1, b1, W2, b2, out, bnpart);
  k_bnstats<<<512,  256, 0, stream>>>(bnpart, bnacc);
  k_bnapply<<<256,  256, 0, stream>>>(out, bnacc, gamma, beta);
}